// Round 3
// baseline (44927.579 us; speedup 1.0000x reference)
//
#include <hip/hip_runtime.h>
#include <hip/hip_bf16.h>
#include <stdint.h>

#define T_SEQ 8192
#define DIMS  2048
#define VOCAB 512
#define GS    ((size_t)VOCAB * DIMS)

typedef unsigned short u16;
typedef unsigned int   uint32;
typedef unsigned long long u64;

__device__ __forceinline__ float lo2f(uint32 u) { return __uint_as_float(u << 16); }
__device__ __forceinline__ float hi2f(uint32 u) { return __uint_as_float(u & 0xffff0000u); }

// ---------------------------------------------------------------- X = Wx.T + bx
__global__ __launch_bounds__(256) void k_build_x(const float* __restrict__ Wx,
                                                 const float* __restrict__ bx,
                                                 float* __restrict__ X) {
  int i = blockIdx.x * 256 + threadIdx.x;      // i = d*VOCAB + v
  int v = i & (VOCAB - 1);
  int d = i >> 9;
  X[(size_t)v * DIMS + d] = Wx[i] + bx[d];
}

// ---------------------------------------------------------------- G_g = X @ Wg.T + bwg
__global__ __launch_bounds__(256) void k_gate_gemm(const float* __restrict__ X,
                                                   const float* __restrict__ Wg,
                                                   const float* __restrict__ bw,
                                                   float* __restrict__ Gout) {
  __shared__ float Xs[32][64];
  __shared__ float Ws[32][64];
  const int v0 = blockIdx.y * 64;
  const int j0 = blockIdx.x * 64;
  const int tid = threadIdx.x;
  const int tx = tid & 15, ty = tid >> 4;
  float acc[4][4] = {{0.f}};
  for (int k0 = 0; k0 < DIMS; k0 += 32) {
    const int r = tid >> 2, q = tid & 3;
    {
      const float* src = X + (size_t)(v0 + r) * DIMS + k0 + q * 8;
      float4 a = ((const float4*)src)[0];
      float4 b = ((const float4*)src)[1];
      Xs[q*8+0][r]=a.x; Xs[q*8+1][r]=a.y; Xs[q*8+2][r]=a.z; Xs[q*8+3][r]=a.w;
      Xs[q*8+4][r]=b.x; Xs[q*8+5][r]=b.y; Xs[q*8+6][r]=b.z; Xs[q*8+7][r]=b.w;
      const float* wsrc = Wg + (size_t)(j0 + r) * DIMS + k0 + q * 8;
      float4 c = ((const float4*)wsrc)[0];
      float4 e = ((const float4*)wsrc)[1];
      Ws[q*8+0][r]=c.x; Ws[q*8+1][r]=c.y; Ws[q*8+2][r]=c.z; Ws[q*8+3][r]=c.w;
      Ws[q*8+4][r]=e.x; Ws[q*8+5][r]=e.y; Ws[q*8+6][r]=e.z; Ws[q*8+7][r]=e.w;
    }
    __syncthreads();
    #pragma unroll
    for (int k = 0; k < 32; ++k) {
      float xa[4], wb[4];
      *(float4*)xa = *(const float4*)&Xs[k][ty*4];
      *(float4*)wb = *(const float4*)&Ws[k][tx*4];
      #pragma unroll
      for (int a = 0; a < 4; ++a)
        #pragma unroll
        for (int b = 0; b < 4; ++b)
          acc[a][b] = fmaf(xa[a], wb[b], acc[a][b]);
    }
    __syncthreads();
  }
  #pragma unroll
  for (int a = 0; a < 4; ++a)
    #pragma unroll
    for (int b = 0; b < 4; ++b)
      Gout[(size_t)(v0 + ty*4 + a) * DIMS + j0 + tx*4 + b] =
          acc[a][b] + bw[j0 + tx*4 + b];
}

// ---------------------------------------------------------------- recurrence
template <typename HS> __device__ __forceinline__ void store_h(HS* hs, size_t idx, float v);
template <> __device__ __forceinline__ void store_h<float>(float* hs, size_t idx, float v) { hs[idx] = v; }
template <> __device__ __forceinline__ void store_h<u16>(u16* hs, size_t idx, float v) {
  __hip_bfloat16 b = __float2bfloat16(v);
  hs[idx] = *reinterpret_cast<u16*>(&b);
}

// Persistent kernel, 256 blocks (1/CU). Wave w of block b owns rows j0+2w, j0+2w+1
// for ALL FOUR gates (8 dots/wave) -> epilogue is wave-local, one barrier/step.
// h published as f32 with step-tag in the low 8 mantissa bits (err 2^-17, tag
// ambiguity needs 512-step skew -> impossible). Double-buffered; selective retry.
// U weights pinned in VGPRs via empty asm (forbids rematerialized global loads).
template <typename HS>
__global__ __launch_bounds__(256, 1) void k_lstm(
    const int* __restrict__ tokens,
    const float* __restrict__ G,
    uint32* hbuf,
    HS* __restrict__ hs,
    const float* __restrict__ Uf, const float* __restrict__ Ui,
    const float* __restrict__ Uc, const float* __restrict__ Uo,
    const float* __restrict__ bUf, const float* __restrict__ bUi,
    const float* __restrict__ bUc, const float* __restrict__ bUo) {
  __shared__ float h_s[DIMS];
  const int tid  = threadIdx.x;
  const int wave = tid >> 6;
  const int lane = tid & 63;
  const int j0   = blockIdx.x * 8;

  // Weight fragments, permuted to match the LDS staging layout:
  // LDS float2 slot s = q*256 + t holds global h-pair 4t+q  (t=thread, q=chunk).
  // Dot at (lane,i) reads slot s = lane+64i -> needs U row pair 4*(s&255)+(s>>8).
  float2 w[8][16];
  #pragma unroll
  for (int g = 0; g < 4; ++g) {
    const float* Ug = (g == 0) ? Uf : (g == 1) ? Ui : (g == 2) ? Uc : Uo;
    #pragma unroll
    for (int p = 0; p < 2; ++p) {
      const float2* rowp = (const float2*)(Ug + (size_t)(j0 + 2 * wave + p) * DIMS);
      #pragma unroll
      for (int i = 0; i < 16; ++i) {
        int s = lane + 64 * i;
        int gidx = 4 * (s & 255) + (s >> 8);
        w[g * 2 + p][i] = rowp[gidx];
      }
    }
  }
  // Pin in registers (VGPR_Count must jump to ~330 — validation signal).
  #pragma unroll
  for (int r = 0; r < 8; ++r)
    #pragma unroll
    for (int i = 0; i < 16; ++i)
      asm volatile("" : "+v"(w[r][i].x), "+v"(w[r][i].y));

  float creg = 0.f, b0 = 0.f, b1 = 0.f, b2 = 0.f, b3 = 0.f;
  float g0 = 0.f, g1 = 0.f, g2 = 0.f, g3 = 0.f;
  int jrow = j0;
  if (lane < 2) {
    jrow = j0 + 2 * wave + lane;
    b0 = bUf[jrow]; b1 = bUi[jrow]; b2 = bUc[jrow]; b3 = bUo[jrow];
    int tok0 = tokens[0];
    g0 = G[0 * GS + (size_t)tok0 * DIMS + jrow];
    g1 = G[1 * GS + (size_t)tok0 * DIMS + jrow];
    g2 = G[2 * GS + (size_t)tok0 * DIMS + jrow];
    g3 = G[3 * GS + (size_t)tok0 * DIMS + jrow];
    // h0 = 0 with tag 0; buffer-1 tag 0 != 1 (and != poison tag 0xAA).
    __hip_atomic_store(&hbuf[jrow], 0u, __ATOMIC_RELAXED, __HIP_MEMORY_SCOPE_AGENT);
    __hip_atomic_store(&hbuf[DIMS + jrow], 0u, __ATOMIC_RELAXED, __HIP_MEMORY_SCOPE_AGENT);
  }

  float2* h2 = (float2*)h_s;
  #pragma unroll 1
  for (int t = 0; t < T_SEQ; ++t) {
    { // stage h_t: poll tags (selective retry), unpack into LDS
      const u64* hsrc = (const u64*)(hbuf + (size_t)(t & 1) * DIMS) + tid * 4;
      const uint32 want = (uint32)t & 0xFFu;
      u64 u[4];
      #pragma unroll
      for (int q = 0; q < 4; ++q)
        u[q] = __hip_atomic_load(&hsrc[q], __ATOMIC_RELAXED, __HIP_MEMORY_SCOPE_AGENT);
      for (;;) {
        bool all = true;
        #pragma unroll
        for (int q = 0; q < 4; ++q) {
          uint32 lo = (uint32)u[q], hi = (uint32)(u[q] >> 32);
          if ((((lo ^ want) | (hi ^ want)) & 0xFFu) != 0u) {
            u[q] = __hip_atomic_load(&hsrc[q], __ATOMIC_RELAXED, __HIP_MEMORY_SCOPE_AGENT);
            all = false;
          }
        }
        if (all) break;
      }
      #pragma unroll
      for (int q = 0; q < 4; ++q)
        h2[q * 256 + tid] = make_float2(__uint_as_float((uint32)u[q]),
                                        __uint_as_float((uint32)(u[q] >> 32)));
    }
    __syncthreads();
    // 8 dots of length 2048 (2 rows x 4 gates), fp32
    float2 a2[8];
    #pragma unroll
    for (int r = 0; r < 8; ++r) a2[r] = make_float2(0.f, 0.f);
    #pragma unroll
    for (int i = 0; i < 16; ++i) {
      float2 hv = h2[lane + 64 * i];
      #pragma unroll
      for (int r = 0; r < 8; ++r) {
        a2[r].x = fmaf(w[r][i].x, hv.x, a2[r].x);
        a2[r].y = fmaf(w[r][i].y, hv.y, a2[r].y);
      }
    }
    float acc[8];
    #pragma unroll
    for (int r = 0; r < 8; ++r) acc[r] = a2[r].x + a2[r].y;
    #pragma unroll
    for (int d = 32; d; d >>= 1)
      #pragma unroll
      for (int r = 0; r < 8; ++r) acc[r] += __shfl_xor(acc[r], d, 64);
    // epilogue: lanes 0,1 own rows j0+2*wave+{0,1}; no cross-wave exchange.
    if (lane < 2) {
      const float yf = acc[0 + lane] + b0 + g0;
      const float yi = acc[2 + lane] + b1 + g1;
      const float yc = acc[4 + lane] + b2 + g2;
      const float yo = acc[6 + lane] + b3 + g3;
      const float fg = 1.f / (1.f + __expf(-yf));
      const float ig = 1.f / (1.f + __expf(-yi));
      const float cn = 1.f - 2.f / (1.f + __expf(2.f * yc));
      const float og = 1.f / (1.f + __expf(-yo));
      creg = fg * creg + ig * cn;
      const float th = 1.f - 2.f / (1.f + __expf(2.f * creg));
      const float hv = og * th;
      const uint32 tb = (__float_as_uint(hv) & 0xFFFFFF00u) | ((uint32)(t + 1) & 0xFFu);
      __hip_atomic_store(&hbuf[(size_t)((t + 1) & 1) * DIMS + jrow], tb,
                         __ATOMIC_RELAXED, __HIP_MEMORY_SCOPE_AGENT);
      store_h<HS>(hs, (size_t)t * DIMS + jrow, __uint_as_float(tb));
      const int tn = (t + 1 < T_SEQ) ? t + 1 : T_SEQ - 1;
      const int tok = tokens[tn];
      g0 = G[0 * GS + (size_t)tok * DIMS + jrow];
      g1 = G[1 * GS + (size_t)tok * DIMS + jrow];
      g2 = G[2 * GS + (size_t)tok * DIMS + jrow];
      g3 = G[3 * GS + (size_t)tok * DIMS + jrow];
    }
    // h_s(t) may only be overwritten after the t+1 poll passes, which requires
    // every wave of this block to have published t+1, i.e. finished reading h_s(t).
  }
}

// ---------------------------------------------------------------- logits = hs @ V.T + bv
template <typename HS> __device__ __forceinline__ void load8(const HS* p, float* o);
template <> __device__ __forceinline__ void load8<float>(const float* p, float* o) {
  float4 a = ((const float4*)p)[0], b = ((const float4*)p)[1];
  o[0]=a.x; o[1]=a.y; o[2]=a.z; o[3]=a.w; o[4]=b.x; o[5]=b.y; o[6]=b.z; o[7]=b.w;
}
template <> __device__ __forceinline__ void load8<u16>(const u16* p, float* o) {
  uint4 u = *(const uint4*)p;
  o[0]=lo2f(u.x); o[1]=hi2f(u.x); o[2]=lo2f(u.y); o[3]=hi2f(u.y);
  o[4]=lo2f(u.z); o[5]=hi2f(u.z); o[6]=lo2f(u.w); o[7]=hi2f(u.w);
}

template <typename HS>
__global__ __launch_bounds__(256) void k_out_gemm(const HS* __restrict__ hs,
                                                  const float* __restrict__ V,
                                                  const float* __restrict__ bvb,
                                                  float* __restrict__ logits) {
  __shared__ float As[32][64];
  __shared__ float Bs[32][128];
  const int t0 = blockIdx.x * 64;
  const int v0 = blockIdx.y * 128;
  const int tid = threadIdx.x;
  const int tx = tid & 15, ty = tid >> 4;
  float acc[4][8] = {{0.f}};
  for (int k0 = 0; k0 < DIMS; k0 += 32) {
    {
      const int r = tid >> 2, q = tid & 3;
      float o8[8];
      load8<HS>(hs + (size_t)(t0 + r) * DIMS + k0 + q * 8, o8);
      #pragma unroll
      for (int s = 0; s < 8; ++s) As[q*8+s][r] = o8[s];
      const int rb = tid >> 1, c0 = (tid & 1) * 2;
      #pragma unroll
      for (int c = 0; c < 2; ++c) {
        float p8[8];
        load8<float>(V + (size_t)(v0 + rb) * DIMS + k0 + (c0 + c) * 8, p8);
        #pragma unroll
        for (int s = 0; s < 8; ++s) Bs[(c0+c)*8+s][rb] = p8[s];
      }
    }
    __syncthreads();
    #pragma unroll
    for (int k = 0; k < 32; ++k) {
      float av[4], bw8[8];
      *(float4*)av = *(const float4*)&As[k][ty*4];
      *(float4*)&bw8[0] = *(const float4*)&Bs[k][tx*8];
      *(float4*)&bw8[4] = *(const float4*)&Bs[k][tx*8+4];
      #pragma unroll
      for (int a = 0; a < 4; ++a)
        #pragma unroll
        for (int b = 0; b < 8; ++b)
          acc[a][b] = fmaf(av[a], bw8[b], acc[a][b]);
    }
    __syncthreads();
  }
  #pragma unroll
  for (int a = 0; a < 4; ++a)
    #pragma unroll
    for (int b = 0; b < 8; ++b)
      logits[(size_t)(t0 + ty*4 + a) * VOCAB + v0 + tx*8 + b] =
          acc[a][b] + bvb[v0 + tx*8 + b];
}

// ---------------------------------------------------------------- log_softmax rows (in-place)
__global__ __launch_bounds__(256) void k_logsoftmax(float* __restrict__ logits) {
  const int t = blockIdx.x;
  const int tid = threadIdx.x;
  float* row = logits + (size_t)t * VOCAB;
  float x0 = row[tid], x1 = row[tid + 256];
  float m = fmaxf(x0, x1);
  #pragma unroll
  for (int d = 32; d; d >>= 1) m = fmaxf(m, __shfl_xor(m, d, 64));
  __shared__ float r1[4], r2[4];
  if ((tid & 63) == 0) r1[tid >> 6] = m;
  __syncthreads();
  m = fmaxf(fmaxf(r1[0], r1[1]), fmaxf(r1[2], r1[3]));
  float s = __expf(x0 - m) + __expf(x1 - m);
  #pragma unroll
  for (int d = 32; d; d >>= 1) s += __shfl_xor(s, d, 64);
  if ((tid & 63) == 0) r2[tid >> 6] = s;
  __syncthreads();
  s = r2[0] + r2[1] + r2[2] + r2[3];
  const float lse = m + __logf(s);
  row[tid] = x0 - lse;
  row[tid + 256] = x1 - lse;
}

// ----------------------------------------------------------------
extern "C" void kernel_launch(void* const* d_in, const int* in_sizes, int n_in,
                              void* d_out, int out_size, void* d_ws, size_t ws_size,
                              hipStream_t stream) {
  const int*   tokens = (const int*)d_in[0];
  const float* Wx  = (const float*)d_in[1];
  const float* bx  = (const float*)d_in[2];
  const float* Uf  = (const float*)d_in[3];
  const float* bUf = (const float*)d_in[4];
  const float* Wf  = (const float*)d_in[5];
  const float* bwf = (const float*)d_in[6];
  const float* Ui  = (const float*)d_in[7];
  const float* bUi = (const float*)d_in[8];
  const float* Wi  = (const float*)d_in[9];
  const float* bwi = (const float*)d_in[10];
  const float* Uc  = (const float*)d_in[11];
  const float* bUc = (const float*)d_in[12];
  const float* Wc  = (const float*)d_in[13];
  const float* bwc = (const float*)d_in[14];
  const float* Uo  = (const float*)d_in[15];
  const float* bUo = (const float*)d_in[16];
  const float* Wo  = (const float*)d_in[17];
  const float* bwo = (const float*)d_in[18];
  const float* V   = (const float*)d_in[19];
  const float* bv  = (const float*)d_in[20];

  char* ws = (char*)d_ws;
  float* X = (float*)ws;                                   // 4 MiB
  float* G = (float*)(ws + 4194304ull);                    // 16 MiB
  uint32* hbuf = (uint32*)(ws + 20971520ull);              // 16 KiB (32 reserved)
  char* rest = ws + 21004288ull;
  const bool f32path = ws_size >= 88113152ull;             // + hs f32 (64 MiB)

  k_build_x<<<dim3((DIMS * VOCAB) / 256), dim3(256), 0, stream>>>(Wx, bx, X);
  dim3 gg(DIMS / 64, VOCAB / 64);
  k_gate_gemm<<<gg, dim3(256), 0, stream>>>(X, Wf, bwf, G + 0 * GS);
  k_gate_gemm<<<gg, dim3(256), 0, stream>>>(X, Wi, bwi, G + 1 * GS);
  k_gate_gemm<<<gg, dim3(256), 0, stream>>>(X, Wc, bwc, G + 2 * GS);
  k_gate_gemm<<<gg, dim3(256), 0, stream>>>(X, Wo, bwo, G + 3 * GS);

  float* logits = (float*)d_out;   // logits built in d_out, log_softmax in-place
  if (f32path) {
    float* hs = (float*)rest;
    k_lstm<float><<<dim3(256), dim3(256), 0, stream>>>(
        tokens, G, hbuf, hs, Uf, Ui, Uc, Uo, bUf, bUi, bUc, bUo);
    k_out_gemm<float><<<dim3(T_SEQ / 64, VOCAB / 128), dim3(256), 0, stream>>>(
        hs, V, bv, logits);
  } else {
    u16* hs = (u16*)rest;
    k_lstm<u16><<<dim3(256), dim3(256), 0, stream>>>(
        tokens, G, hbuf, hs, Uf, Ui, Uc, Uo, bUf, bUi, bUc, bUo);
    k_out_gemm<u16><<<dim3(T_SEQ / 64, VOCAB / 128), dim3(256), 0, stream>>>(
        hs, V, bv, logits);
  }
  k_logsoftmax<<<dim3(T_SEQ), dim3(256), 0, stream>>>(logits);
}

// Round 4
// 30282.260 us; speedup vs baseline: 1.4836x; 1.4836x over previous
//
#include <hip/hip_runtime.h>
#include <hip/hip_bf16.h>
#include <stdint.h>

#define T_SEQ 8192
#define DIMS  2048
#define VOCAB 512
#define GS    ((size_t)VOCAB * DIMS)

typedef unsigned short u16;
typedef unsigned int   uint32;
typedef unsigned long long u64;

__device__ __forceinline__ float lo2f(uint32 u) { return __uint_as_float(u << 16); }
__device__ __forceinline__ float hi2f(uint32 u) { return __uint_as_float(u & 0xffff0000u); }

// ---------------------------------------------------------------- X = Wx.T + bx
__global__ __launch_bounds__(256) void k_build_x(const float* __restrict__ Wx,
                                                 const float* __restrict__ bx,
                                                 float* __restrict__ X) {
  int i = blockIdx.x * 256 + threadIdx.x;      // i = d*VOCAB + v
  int v = i & (VOCAB - 1);
  int d = i >> 9;
  X[(size_t)v * DIMS + d] = Wx[i] + bx[d];
}

// ---------------------------------------------------------------- G_g = X @ Wg.T + bwg
// Output interleaved by gate: G4[(v*DIMS + j)*4 + gate], so the recurrence
// fetches all 4 gate pre-activations for row j with ONE float4 load.
__global__ __launch_bounds__(256) void k_gate_gemm(const float* __restrict__ X,
                                                   const float* __restrict__ Wg,
                                                   const float* __restrict__ bw,
                                                   float* __restrict__ Gout,
                                                   int gate) {
  __shared__ float Xs[32][64];
  __shared__ float Ws[32][64];
  const int v0 = blockIdx.y * 64;
  const int j0 = blockIdx.x * 64;
  const int tid = threadIdx.x;
  const int tx = tid & 15, ty = tid >> 4;
  float acc[4][4] = {{0.f}};
  for (int k0 = 0; k0 < DIMS; k0 += 32) {
    const int r = tid >> 2, q = tid & 3;
    {
      const float* src = X + (size_t)(v0 + r) * DIMS + k0 + q * 8;
      float4 a = ((const float4*)src)[0];
      float4 b = ((const float4*)src)[1];
      Xs[q*8+0][r]=a.x; Xs[q*8+1][r]=a.y; Xs[q*8+2][r]=a.z; Xs[q*8+3][r]=a.w;
      Xs[q*8+4][r]=b.x; Xs[q*8+5][r]=b.y; Xs[q*8+6][r]=b.z; Xs[q*8+7][r]=b.w;
      const float* wsrc = Wg + (size_t)(j0 + r) * DIMS + k0 + q * 8;
      float4 c = ((const float4*)wsrc)[0];
      float4 e = ((const float4*)wsrc)[1];
      Ws[q*8+0][r]=c.x; Ws[q*8+1][r]=c.y; Ws[q*8+2][r]=c.z; Ws[q*8+3][r]=c.w;
      Ws[q*8+4][r]=e.x; Ws[q*8+5][r]=e.y; Ws[q*8+6][r]=e.z; Ws[q*8+7][r]=e.w;
    }
    __syncthreads();
    #pragma unroll
    for (int k = 0; k < 32; ++k) {
      float xa[4], wb[4];
      *(float4*)xa = *(const float4*)&Xs[k][ty*4];
      *(float4*)wb = *(const float4*)&Ws[k][tx*4];
      #pragma unroll
      for (int a = 0; a < 4; ++a)
        #pragma unroll
        for (int b = 0; b < 4; ++b)
          acc[a][b] = fmaf(xa[a], wb[b], acc[a][b]);
    }
    __syncthreads();
  }
  #pragma unroll
  for (int a = 0; a < 4; ++a)
    #pragma unroll
    for (int b = 0; b < 4; ++b)
      Gout[(((size_t)(v0 + ty*4 + a) * DIMS + j0 + tx*4 + b) << 2) + gate] =
          acc[a][b] + bw[j0 + tx*4 + b];
}

// ---------------------------------------------------------------- recurrence
template <typename HS> __device__ __forceinline__ void store_h(HS* hs, size_t idx, float v);
template <> __device__ __forceinline__ void store_h<float>(float* hs, size_t idx, float v) { hs[idx] = v; }
template <> __device__ __forceinline__ void store_h<u16>(u16* hs, size_t idx, float v) {
  __hip_bfloat16 b = __float2bfloat16(v);
  hs[idx] = *reinterpret_cast<u16*>(&b);
}

// Persistent kernel: 256 blocks x 512 threads (8 waves, 2/SIMD). Wave w owns
// h-row j0+w; lane group (lane>>4) owns one gate, 16 sub-lanes split k.
// Weights: 32 float4/lane = 128 VGPRs -> fits under the 256-reg cap (round-2/3
// post-mortem: 256 floats/lane spills to scratch; 128 does not).
// h published as f32 with 8-bit step tag in the mantissa LSBs (err 2^-17).
// LDS h double-buffered by step parity; ONE barrier/step (after staging).
// Safety: a wave can only restage buffer p at step t+2 after its t+1 poll
// passes, which requires remote blocks to have consumed ALL of h_t, which
// requires every sibling wave to have published tag t+1 (i.e. finished
// reading buffer p at step t). No WAR race (round-3 race fixed).
template <typename HS>
__global__ __launch_bounds__(512, 2) void k_lstm(
    const int* __restrict__ tokens,
    const float4* __restrict__ G4,
    uint32* hbuf,
    HS* __restrict__ hs,
    const float* __restrict__ Uf, const float* __restrict__ Ui,
    const float* __restrict__ Uc, const float* __restrict__ Uo,
    const float* __restrict__ bUf, const float* __restrict__ bUi,
    const float* __restrict__ bUc, const float* __restrict__ bUo) {
  __shared__ float4 h4[2][DIMS / 4];
  const int tid  = threadIdx.x;          // 0..511
  const int wave = tid >> 6;             // 0..7
  const int lane = tid & 63;
  const int gate = lane >> 4;            // 0..3 -> f,i,c,o
  const int sl   = lane & 15;            // k-split within gate group
  const int jr   = blockIdx.x * 8 + wave;

  const float* Ug = (gate == 0) ? Uf : (gate == 1) ? Ui : (gate == 2) ? Uc : Uo;
  const float4* urow = (const float4*)(Ug + (size_t)jr * DIMS);
  float4 w[32];
  #pragma unroll
  for (int i = 0; i < 32; ++i) w[i] = urow[sl + 16 * i];
  #pragma unroll
  for (int i = 0; i < 32; ++i)
    asm volatile("" : "+v"(w[i].x), "+v"(w[i].y), "+v"(w[i].z), "+v"(w[i].w));

  float creg = 0.f, bF = 0.f, bI = 0.f, bC = 0.f, bO = 0.f;
  float4 gv = make_float4(0.f, 0.f, 0.f, 0.f);
  if (lane == 0) {
    bF = bUf[jr]; bI = bUi[jr]; bC = bUc[jr]; bO = bUo[jr];
    const int tok0 = tokens[0];
    gv = G4[(size_t)tok0 * DIMS + jr];
    // h0 = 0 with tag 0; buffer-1 tag 0 (!= 1, != poison 0xAA).
    __hip_atomic_store(&hbuf[jr], 0u, __ATOMIC_RELAXED, __HIP_MEMORY_SCOPE_AGENT);
    __hip_atomic_store(&hbuf[DIMS + jr], 0u, __ATOMIC_RELAXED, __HIP_MEMORY_SCOPE_AGENT);
  }

  #pragma unroll 1
  for (int t = 0; t < T_SEQ; ++t) {
    { // stage h_t: thread tid owns h[4*tid..4*tid+3]; poll tags, selective retry
      const u64* hsrc = (const u64*)(hbuf + (size_t)(t & 1) * DIMS) + 2 * tid;
      const uint32 want = (uint32)t & 0xFFu;
      u64 u0 = __hip_atomic_load(hsrc + 0, __ATOMIC_RELAXED, __HIP_MEMORY_SCOPE_AGENT);
      u64 u1 = __hip_atomic_load(hsrc + 1, __ATOMIC_RELAXED, __HIP_MEMORY_SCOPE_AGENT);
      for (;;) {
        const bool ok0 = ((((uint32)u0 ^ want) | ((uint32)(u0 >> 32) ^ want)) & 0xFFu) == 0u;
        const bool ok1 = ((((uint32)u1 ^ want) | ((uint32)(u1 >> 32) ^ want)) & 0xFFu) == 0u;
        if (ok0 && ok1) break;
        if (!ok0) u0 = __hip_atomic_load(hsrc + 0, __ATOMIC_RELAXED, __HIP_MEMORY_SCOPE_AGENT);
        if (!ok1) u1 = __hip_atomic_load(hsrc + 1, __ATOMIC_RELAXED, __HIP_MEMORY_SCOPE_AGENT);
      }
      h4[t & 1][tid] = make_float4(__uint_as_float((uint32)u0),
                                   __uint_as_float((uint32)(u0 >> 32)),
                                   __uint_as_float((uint32)u1),
                                   __uint_as_float((uint32)(u1 >> 32)));
    }
    __syncthreads();
    // one dot of length 2048, split: gate group reads all h, sub-lane covers 128 k
    const float4* hb = h4[t & 1];
    float4 a4 = make_float4(0.f, 0.f, 0.f, 0.f);
    #pragma unroll
    for (int i = 0; i < 32; ++i) {
      float4 hv = hb[sl + 16 * i];
      a4.x = fmaf(w[i].x, hv.x, a4.x);
      a4.y = fmaf(w[i].y, hv.y, a4.y);
      a4.z = fmaf(w[i].z, hv.z, a4.z);
      a4.w = fmaf(w[i].w, hv.w, a4.w);
    }
    float acc = (a4.x + a4.y) + (a4.z + a4.w);
    #pragma unroll
    for (int d = 1; d <= 8; d <<= 1) acc += __shfl_xor(acc, d, 64);
    // gather the 4 gate sums to lane 0 (constant source lanes)
    const float sI = __shfl(acc, 16, 64);
    const float sC = __shfl(acc, 32, 64);
    const float sO = __shfl(acc, 48, 64);
    if (lane == 0) {
      const float yf = acc + bF + gv.x;
      const float yi = sI  + bI + gv.y;
      const float yc = sC  + bC + gv.z;
      const float yo = sO  + bO + gv.w;
      const float fg = 1.f / (1.f + __expf(-yf));
      const float ig = 1.f / (1.f + __expf(-yi));
      const float cn = 1.f - 2.f / (1.f + __expf(2.f * yc));
      const float og = 1.f / (1.f + __expf(-yo));
      creg = fg * creg + ig * cn;
      const float th = 1.f - 2.f / (1.f + __expf(2.f * creg));
      const float hv = og * th;
      const uint32 tb = (__float_as_uint(hv) & 0xFFFFFF00u) | ((uint32)(t + 1) & 0xFFu);
      __hip_atomic_store(&hbuf[(size_t)((t + 1) & 1) * DIMS + jr], tb,
                         __ATOMIC_RELAXED, __HIP_MEMORY_SCOPE_AGENT);
      store_h<HS>(hs, (size_t)t * DIMS + jr, __uint_as_float(tb));
      const int tn = (t + 1 < T_SEQ) ? t + 1 : T_SEQ - 1;
      const int tok = tokens[tn];
      gv = G4[(size_t)tok * DIMS + jr];        // prefetch gates for t+1
    }
  }
}

// ---------------------------------------------------------------- logits = hs @ V.T + bv
template <typename HS> __device__ __forceinline__ void load8(const HS* p, float* o);
template <> __device__ __forceinline__ void load8<float>(const float* p, float* o) {
  float4 a = ((const float4*)p)[0], b = ((const float4*)p)[1];
  o[0]=a.x; o[1]=a.y; o[2]=a.z; o[3]=a.w; o[4]=b.x; o[5]=b.y; o[6]=b.z; o[7]=b.w;
}
template <> __device__ __forceinline__ void load8<u16>(const u16* p, float* o) {
  uint4 u = *(const uint4*)p;
  o[0]=lo2f(u.x); o[1]=hi2f(u.x); o[2]=lo2f(u.y); o[3]=hi2f(u.y);
  o[4]=lo2f(u.z); o[5]=hi2f(u.z); o[6]=lo2f(u.w); o[7]=hi2f(u.w);
}

template <typename HS>
__global__ __launch_bounds__(256) void k_out_gemm(const HS* __restrict__ hs,
                                                  const float* __restrict__ V,
                                                  const float* __restrict__ bvb,
                                                  float* __restrict__ logits) {
  __shared__ float As[32][64];
  __shared__ float Bs[32][128];
  const int t0 = blockIdx.x * 64;
  const int v0 = blockIdx.y * 128;
  const int tid = threadIdx.x;
  const int tx = tid & 15, ty = tid >> 4;
  float acc[4][8] = {{0.f}};
  for (int k0 = 0; k0 < DIMS; k0 += 32) {
    {
      const int r = tid >> 2, q = tid & 3;
      float o8[8];
      load8<HS>(hs + (size_t)(t0 + r) * DIMS + k0 + q * 8, o8);
      #pragma unroll
      for (int s = 0; s < 8; ++s) As[q*8+s][r] = o8[s];
      const int rb = tid >> 1, c0 = (tid & 1) * 2;
      #pragma unroll
      for (int c = 0; c < 2; ++c) {
        float p8[8];
        load8<float>(V + (size_t)(v0 + rb) * DIMS + k0 + (c0 + c) * 8, p8);
        #pragma unroll
        for (int s = 0; s < 8; ++s) Bs[(c0+c)*8+s][rb] = p8[s];
      }
    }
    __syncthreads();
    #pragma unroll
    for (int k = 0; k < 32; ++k) {
      float av[4], bw8[8];
      *(float4*)av = *(const float4*)&As[k][ty*4];
      *(float4*)&bw8[0] = *(const float4*)&Bs[k][tx*8];
      *(float4*)&bw8[4] = *(const float4*)&Bs[k][tx*8+4];
      #pragma unroll
      for (int a = 0; a < 4; ++a)
        #pragma unroll
        for (int b = 0; b < 8; ++b)
          acc[a][b] = fmaf(av[a], bw8[b], acc[a][b]);
    }
    __syncthreads();
  }
  #pragma unroll
  for (int a = 0; a < 4; ++a)
    #pragma unroll
    for (int b = 0; b < 8; ++b)
      logits[(size_t)(t0 + ty*4 + a) * VOCAB + v0 + tx*8 + b] =
          acc[a][b] + bvb[v0 + tx*8 + b];
}

// ---------------------------------------------------------------- log_softmax rows (in-place)
__global__ __launch_bounds__(256) void k_logsoftmax(float* __restrict__ logits) {
  const int t = blockIdx.x;
  const int tid = threadIdx.x;
  float* row = logits + (size_t)t * VOCAB;
  float x0 = row[tid], x1 = row[tid + 256];
  float m = fmaxf(x0, x1);
  #pragma unroll
  for (int d = 32; d; d >>= 1) m = fmaxf(m, __shfl_xor(m, d, 64));
  __shared__ float r1[4], r2[4];
  if ((tid & 63) == 0) r1[tid >> 6] = m;
  __syncthreads();
  m = fmaxf(fmaxf(r1[0], r1[1]), fmaxf(r1[2], r1[3]));
  float s = __expf(x0 - m) + __expf(x1 - m);
  #pragma unroll
  for (int d = 32; d; d >>= 1) s += __shfl_xor(s, d, 64);
  if ((tid & 63) == 0) r2[tid >> 6] = s;
  __syncthreads();
  s = r2[0] + r2[1] + r2[2] + r2[3];
  const float lse = m + __logf(s);
  row[tid] = x0 - lse;
  row[tid + 256] = x1 - lse;
}

// ----------------------------------------------------------------
extern "C" void kernel_launch(void* const* d_in, const int* in_sizes, int n_in,
                              void* d_out, int out_size, void* d_ws, size_t ws_size,
                              hipStream_t stream) {
  const int*   tokens = (const int*)d_in[0];
  const float* Wx  = (const float*)d_in[1];
  const float* bx  = (const float*)d_in[2];
  const float* Uf  = (const float*)d_in[3];
  const float* bUf = (const float*)d_in[4];
  const float* Wf  = (const float*)d_in[5];
  const float* bwf = (const float*)d_in[6];
  const float* Ui  = (const float*)d_in[7];
  const float* bUi = (const float*)d_in[8];
  const float* Wi  = (const float*)d_in[9];
  const float* bwi = (const float*)d_in[10];
  const float* Uc  = (const float*)d_in[11];
  const float* bUc = (const float*)d_in[12];
  const float* Wc  = (const float*)d_in[13];
  const float* bwc = (const float*)d_in[14];
  const float* Uo  = (const float*)d_in[15];
  const float* bUo = (const float*)d_in[16];
  const float* Wo  = (const float*)d_in[17];
  const float* bwo = (const float*)d_in[18];
  const float* V   = (const float*)d_in[19];
  const float* bv  = (const float*)d_in[20];

  char* ws = (char*)d_ws;
  float* X = (float*)ws;                                   // 4 MiB
  float* G = (float*)(ws + 4194304ull);                    // 16 MiB (gate-interleaved)
  uint32* hbuf = (uint32*)(ws + 20971520ull);              // 16 KiB (32 reserved)
  char* rest = ws + 21004288ull;
  const bool f32path = ws_size >= 88113152ull;             // + hs f32 (64 MiB)

  k_build_x<<<dim3((DIMS * VOCAB) / 256), dim3(256), 0, stream>>>(Wx, bx, X);
  dim3 gg(DIMS / 64, VOCAB / 64);
  k_gate_gemm<<<gg, dim3(256), 0, stream>>>(X, Wf, bwf, G, 0);
  k_gate_gemm<<<gg, dim3(256), 0, stream>>>(X, Wi, bwi, G, 1);
  k_gate_gemm<<<gg, dim3(256), 0, stream>>>(X, Wc, bwc, G, 2);
  k_gate_gemm<<<gg, dim3(256), 0, stream>>>(X, Wo, bwo, G, 3);

  float* logits = (float*)d_out;   // logits built in d_out, log_softmax in-place
  if (f32path) {
    float* hs = (float*)rest;
    k_lstm<float><<<dim3(256), dim3(512), 0, stream>>>(
        tokens, (const float4*)G, hbuf, hs, Uf, Ui, Uc, Uo, bUf, bUi, bUc, bUo);
    k_out_gemm<float><<<dim3(T_SEQ / 64, VOCAB / 128), dim3(256), 0, stream>>>(
        hs, V, bv, logits);
  } else {
    u16* hs = (u16*)rest;
    k_lstm<u16><<<dim3(256), dim3(512), 0, stream>>>(
        tokens, (const float4*)G, hbuf, hs, Uf, Ui, Uc, Uo, bUf, bUi, bUc, bUo);
    k_out_gemm<u16><<<dim3(T_SEQ / 64, VOCAB / 128), dim3(256), 0, stream>>>(
        hs, V, bv, logits);
  }
  k_logsoftmax<<<dim3(T_SEQ), dim3(256), 0, stream>>>(logits);
}